// Round 11
// baseline (71.329 us; speedup 1.0000x reference)
//
#include <hip/hip_runtime.h>

// Problem constants (from reference setup_inputs)
#define B_DIM 8
#define F_DIM 16384
#define K_DIM 3
#define M_DIM 64
#define LOG2E 1.4426950408889634f

// ---- G-path ws layout (floats; every slot overwritten every launch) ----
//   [0, 65536)          : S partials  slot = m*1024 + b*128 + fc   (fc: 128-f chunk)
//   [65536, 131072)     : Q partials  (same indexing)
//   [131072, +8388608)  : G[b][f][m]  raw per-face 4-exp sums (33.5 MB)
#define WS_Q   65536
#define WS_G   131072
#define WS_NEED ((size_t)(WS_G + (size_t)B_DIM * F_DIM * M_DIM) * sizeof(float))

// ---- fallback ws layout (proven R7 path) ----
#define FB_WS_Q 32768

// ===========================================================================
// Kernel G: G[b,f,m] = sum_j exp2(arg(n_f, w_{m,j}))  (raw, no /16)
// grid = 2048 (b8 x fc256 of 64 f), block = 256 = 64 f x 4 mq (16 m each).
// All lanes of a wave share mq -> sW reads are broadcast (conflict-free).
// ===========================================================================
__global__ __launch_bounds__(256) void fkc_g_kernel(
    const float* __restrict__ normals,   // [B,3,F]
    const float* __restrict__ walpha,    // [M*4]
    const float* __restrict__ wbeta,     // [M*4]
    float* __restrict__ G)               // [B,F,M]
{
    __shared__ float4 sW[256];
    const int tid = threadIdx.x;
    {   // build prescaled kernel-point table (||p||^2==1 folded in)
        float a = walpha[tid], b = wbeta[tid];
        float sa = sinf(a), ca = cosf(a);
        float sb = sinf(b), cb = cosf(b);
        float wx = sa * cb, wy = sa * sb, wz = ca;
        float w2 = wx * wx + wy * wy + wz * wz;
        sW[tid] = make_float4(wx * 25.0f * LOG2E, wy * 25.0f * LOG2E,
                              wz * 25.0f * LOG2E, -12.5f * LOG2E * (w2 + 1.0f));
    }
    __syncthreads();

    const int b  = blockIdx.x >> 8;          // 256 blocks per batch
    const int fc = blockIdx.x & 255;         // 64-f chunk
    const int fl = tid & 63, mq = tid >> 6;  // lane=f, wave=mq
    const int f  = (fc << 6) + fl;

    const float* nb = normals + (size_t)b * 3 * F_DIM;
    const float px = nb[f], py = nb[F_DIM + f], pz = nb[2 * F_DIM + f];

    float4* gp = (float4*)(G + ((size_t)(b * F_DIM + f)) * M_DIM + mq * 16);
#pragma unroll
    for (int r = 0; r < 4; ++r) {            // 4 float4 = 16 m per thread
        float v[4];
#pragma unroll
        for (int c = 0; c < 4; ++c) {
            const int m = mq * 16 + r * 4 + c;
            float4 w0 = sW[m * 4 + 0], w1 = sW[m * 4 + 1];
            float4 w2 = sW[m * 4 + 2], w3 = sW[m * 4 + 3];
            float e0 = __builtin_amdgcn_exp2f(fmaf(w0.x, px, fmaf(w0.y, py, fmaf(w0.z, pz, w0.w))));
            float e1 = __builtin_amdgcn_exp2f(fmaf(w1.x, px, fmaf(w1.y, py, fmaf(w1.z, pz, w1.w))));
            float e2 = __builtin_amdgcn_exp2f(fmaf(w2.x, px, fmaf(w2.y, py, fmaf(w2.z, pz, w2.w))));
            float e3 = __builtin_amdgcn_exp2f(fmaf(w3.x, px, fmaf(w3.y, py, fmaf(w3.z, pz, w3.w))));
            v[c] = (e0 + e1) + (e2 + e3);
        }
        gp[r] = make_float4(v[0], v[1], v[2], v[3]);
    }
}

// ===========================================================================
// Kernel GATHER: feat_raw[b,m,f] = G[f] + G[i1] + G[i2] + G[i3] -> out,
// plus per-(m,b,fc) partials via padded-LDS transpose (2-way conflicts only).
// grid = 1024 (b8 x fc128 of 128 f), block = 256 = 128 f x 2 mh (32 m each).
// ===========================================================================
__global__ __launch_bounds__(256) void fkc_gather_kernel(
    const float* __restrict__ G,         // [B,F,M]
    const int*   __restrict__ nidx,      // [B,F,K]
    float* __restrict__ out,             // [B,M,F] raw sums
    float* __restrict__ ws)
{
    __shared__ float T[2][128][34];      // padded: bank stride 34 -> 2-way max
    const int tid = threadIdx.x;
    const int b  = blockIdx.x >> 7;          // 128 blocks per batch
    const int fc = blockIdx.x & 127;         // 128-f chunk
    const int fl = tid & 127, mh = tid >> 7; // lane-major f, 2 m-halves
    const int f  = (fc << 7) + fl;

    const int* ib = nidx + ((size_t)(b * F_DIM + f)) * K_DIM;
    const int i1 = ib[0], i2 = ib[1], i3 = ib[2];

    const size_t gb = (size_t)b * F_DIM * M_DIM + (size_t)mh * 32;
    const float4* r0 = (const float4*)(G + gb + (size_t)f  * M_DIM);
    const float4* r1 = (const float4*)(G + gb + (size_t)i1 * M_DIM);
    const float4* r2 = (const float4*)(G + gb + (size_t)i2 * M_DIM);
    const float4* r3 = (const float4*)(G + gb + (size_t)i3 * M_DIM);

    float4 acc[8];
#pragma unroll
    for (int r = 0; r < 8; ++r) {
        float4 a = r0[r], c = r1[r], d = r2[r], e = r3[r];
        acc[r] = make_float4((a.x + c.x) + (d.x + e.x), (a.y + c.y) + (d.y + e.y),
                             (a.z + c.z) + (d.z + e.z), (a.w + c.w) + (d.w + e.w));
    }

    // raw feat -> out (coalesced per m across lanes)
    {
        float* ob = out + ((size_t)b * M_DIM + mh * 32) * F_DIM + f;
#pragma unroll
        for (int r = 0; r < 8; ++r) {
            ob[(size_t)(r * 4 + 0) * F_DIM] = acc[r].x;
            ob[(size_t)(r * 4 + 1) * F_DIM] = acc[r].y;
            ob[(size_t)(r * 4 + 2) * F_DIM] = acc[r].z;
            ob[(size_t)(r * 4 + 3) * F_DIM] = acc[r].w;
        }
    }

    // ---- partials: pass A (sum), pass B (sumsq) through the LDS transpose ----
    const int rmh = tid >> 7, rml = (tid >> 2) & 31, rfs = tid & 3;
    float ps;
#pragma unroll
    for (int r = 0; r < 8; ++r) {
        *(float2*)&T[mh][fl][r * 4 + 0] = make_float2(acc[r].x, acc[r].y);
        *(float2*)&T[mh][fl][r * 4 + 2] = make_float2(acc[r].z, acc[r].w);
    }
    __syncthreads();
    {
        float s = 0.f;
#pragma unroll
        for (int i = 0; i < 32; ++i) s += T[rmh][rfs * 32 + i][rml];
        s += __shfl_xor(s, 1, 64);
        s += __shfl_xor(s, 2, 64);
        ps = s;                              // valid where rfs==0
    }
    __syncthreads();
#pragma unroll
    for (int r = 0; r < 8; ++r) {
        *(float2*)&T[mh][fl][r * 4 + 0] = make_float2(acc[r].x * acc[r].x, acc[r].y * acc[r].y);
        *(float2*)&T[mh][fl][r * 4 + 2] = make_float2(acc[r].z * acc[r].z, acc[r].w * acc[r].w);
    }
    __syncthreads();
    {
        float q = 0.f;
#pragma unroll
        for (int i = 0; i < 32; ++i) q += T[rmh][rfs * 32 + i][rml];
        q += __shfl_xor(q, 1, 64);
        q += __shfl_xor(q, 2, 64);
        if (rfs == 0) {
            int m = rmh * 32 + rml;
            int slot = m * 1024 + b * 128 + fc;
            ws[slot] = ps;
            ws[WS_Q + slot] = q;
        }
    }
}

// ===========================================================================
// Kernel BN: stats + BN + ReLU. grid = 512 (one (b,m) row), block = 256.
// out holds RAW sums S (= 16*feat). /16 folded into coefficients.
// ===========================================================================
__global__ __launch_bounds__(256) void fkc_bn2_kernel(
    float* __restrict__ out,
    const float* __restrict__ gamma,
    const float* __restrict__ beta,
    const float* __restrict__ ws)
{
    __shared__ float sS[4], sQ[4];
    __shared__ float sAC[2];
    const int row = blockIdx.x;              // b*64 + m
    const int m = row & 63;
    const int tid = threadIdx.x;
    const int wave = tid >> 6, lane = tid & 63;

    {   // fold this channel's 1024 partials (4 per thread, L2-hot)
        const float* p = ws + m * 1024;
        const float* r = ws + WS_Q + m * 1024;
        float s = (p[tid] + p[tid + 256]) + (p[tid + 512] + p[tid + 768]);
        float q = (r[tid] + r[tid + 256]) + (r[tid + 512] + r[tid + 768]);
#pragma unroll
        for (int off = 32; off >= 1; off >>= 1) {
            s += __shfl_xor(s, off, 64);
            q += __shfl_xor(q, off, 64);
        }
        if (lane == 0) { sS[wave] = s; sQ[wave] = q; }
    }
    __syncthreads();
    if (tid == 0) {
        float s = (sS[0] + sS[1]) + (sS[2] + sS[3]);
        float q = (sQ[0] + sQ[1]) + (sQ[2] + sQ[3]);
        const float invcnt = 1.0f / (float)(B_DIM * F_DIM);
        float meanS = s * invcnt;
        float meanF = meanS * (1.0f / 16.0f);
        float ef2   = q * invcnt * (1.0f / 256.0f);
        float var   = ef2 - meanF * meanF;
        float inv   = rsqrtf(var + 1e-5f);
        float A = gamma[m] * inv;
        sAC[0] = A * (1.0f / 16.0f);          // applied to raw S
        sAC[1] = beta[m] - meanF * A;
    }
    __syncthreads();

    const float A = sAC[0], C = sAC[1];
    float4* p4 = (float4*)(out + (size_t)row * F_DIM);
#pragma unroll
    for (int i = 0; i < 16; ++i) {
        float4 v = p4[tid + i * 256];
        v.x = fmaxf(fmaf(v.x, A, C), 0.0f);
        v.y = fmaxf(fmaf(v.y, A, C), 0.0f);
        v.z = fmaxf(fmaf(v.z, A, C), 0.0f);
        v.w = fmaxf(fmaf(v.w, A, C), 0.0f);
        p4[tid + i * 256] = v;
    }
}

// ===========================================================================
// Fallback path: proven 50.85us 2-dispatch pipeline (used iff ws too small).
// ===========================================================================
__global__ __launch_bounds__(256) void fb_feat_kernel(
    const float* __restrict__ normals, const float* __restrict__ walpha,
    const float* __restrict__ wbeta, const int* __restrict__ nidx,
    float* __restrict__ feat_out, float* __restrict__ ws)
{
    __shared__ float4 sW[64];
    __shared__ float sRS[16][32], sRQ[16][32];
    const int tid = threadIdx.x;
    const int b  = blockIdx.x >> 8;
    const int mc = (blockIdx.x >> 6) & 3;
    const int fc = blockIdx.x & 63;
    if (tid < 64) {
        int idx = mc * 64 + tid;
        float a = walpha[idx], bb = wbeta[idx];
        float sa = sinf(a), ca = cosf(a);
        float sb = sinf(bb), cb = cosf(bb);
        float wx = sa * cb, wy = sa * sb, wz = ca;
        float w2 = wx * wx + wy * wy + wz * wz;
        sW[tid] = make_float4(wx * 25.0f * LOG2E, wy * 25.0f * LOG2E,
                              wz * 25.0f * LOG2E, -12.5f * LOG2E * (w2 + 1.0f));
    }
    __syncthreads();
    const int f = (fc << 8) + tid;
    const float* nb = normals + (size_t)b * 3 * F_DIM;
    float px[4], py[4], pz[4];
    px[0] = nb[f]; py[0] = nb[F_DIM + f]; pz[0] = nb[2 * F_DIM + f];
    const int* ib = nidx + ((size_t)b * F_DIM + f) * K_DIM;
#pragma unroll
    for (int k = 0; k < K_DIM; ++k) {
        int id = ib[k];
        px[k + 1] = nb[id]; py[k + 1] = nb[F_DIM + id]; pz[k + 1] = nb[2 * F_DIM + id];
    }
    const int wave = tid >> 6, lane = tid & 63;
    float* outb = feat_out + ((size_t)b * M_DIM + mc * 16) * F_DIM + f;
#pragma unroll 2
    for (int m = 0; m < 16; ++m) {
        float s0 = 0.f, s1 = 0.f, s2 = 0.f, s3 = 0.f;
#pragma unroll
        for (int j = 0; j < 4; ++j) {
            float4 w = sW[m * 4 + j];
            s0 += __builtin_amdgcn_exp2f(fmaf(w.x, px[0], fmaf(w.y, py[0], fmaf(w.z, pz[0], w.w))));
            s1 += __builtin_amdgcn_exp2f(fmaf(w.x, px[1], fmaf(w.y, py[1], fmaf(w.z, pz[1], w.w))));
            s2 += __builtin_amdgcn_exp2f(fmaf(w.x, px[2], fmaf(w.y, py[2], fmaf(w.z, pz[2], w.w))));
            s3 += __builtin_amdgcn_exp2f(fmaf(w.x, px[3], fmaf(w.y, py[3], fmaf(w.z, pz[3], w.w))));
        }
        float fv = ((s0 + s1) + (s2 + s3)) * (1.0f / 16.0f);
        outb[(size_t)m * F_DIM] = fv;
        float s = fv, q = fv * fv;
        s += __shfl_xor(s, 8, 64);  q += __shfl_xor(q, 8, 64);
        s += __shfl_xor(s, 16, 64); q += __shfl_xor(q, 16, 64);
        s += __shfl_xor(s, 32, 64); q += __shfl_xor(q, 32, 64);
        if (lane < 8) { sRS[m][wave * 8 + lane] = s; sRQ[m][wave * 8 + lane] = q; }
    }
    __syncthreads();
    {
        const int m = tid >> 4, j = tid & 15;
        float s = sRS[m][j] + sRS[m][j + 16];
        float q = sRQ[m][j] + sRQ[m][j + 16];
        s += __shfl_xor(s, 1, 64);  q += __shfl_xor(q, 1, 64);
        s += __shfl_xor(s, 2, 64);  q += __shfl_xor(q, 2, 64);
        s += __shfl_xor(s, 4, 64);  q += __shfl_xor(q, 4, 64);
        s += __shfl_xor(s, 8, 64);  q += __shfl_xor(q, 8, 64);
        if (j == 0) {
            int slot = (mc * 16 + m) * 512 + b * 64 + fc;
            ws[slot] = s;
            ws[FB_WS_Q + slot] = q;
        }
    }
}

__global__ __launch_bounds__(256) void fb_bn_kernel(
    float* __restrict__ out, const float* __restrict__ gamma,
    const float* __restrict__ beta, const float* __restrict__ ws)
{
    __shared__ float sS[4], sQ[4];
    __shared__ float sAC[2];
    const int row = blockIdx.x;
    const int m = row & 63;
    const int tid = threadIdx.x;
    const int wave = tid >> 6, lane = tid & 63;
    {
        float s = ws[m * 512 + tid]           + ws[m * 512 + tid + 256];
        float q = ws[FB_WS_Q + m * 512 + tid] + ws[FB_WS_Q + m * 512 + tid + 256];
#pragma unroll
        for (int off = 32; off >= 1; off >>= 1) {
            s += __shfl_xor(s, off, 64);
            q += __shfl_xor(q, off, 64);
        }
        if (lane == 0) { sS[wave] = s; sQ[wave] = q; }
    }
    __syncthreads();
    if (tid == 0) {
        float s = (sS[0] + sS[1]) + (sS[2] + sS[3]);
        float q = (sQ[0] + sQ[1]) + (sQ[2] + sQ[3]);
        const float invcnt = 1.0f / (float)(B_DIM * F_DIM);
        float mean = s * invcnt;
        float var  = q * invcnt - mean * mean;
        float inv  = rsqrtf(var + 1e-5f);
        float A = gamma[m] * inv;
        sAC[0] = A;
        sAC[1] = beta[m] - mean * A;
    }
    __syncthreads();
    const float A = sAC[0], C = sAC[1];
    float4* p4 = (float4*)(out + (size_t)row * F_DIM);
#pragma unroll
    for (int i = 0; i < 16; ++i) {
        float4 v = p4[tid + i * 256];
        v.x = fmaxf(fmaf(v.x, A, C), 0.0f);
        v.y = fmaxf(fmaf(v.y, A, C), 0.0f);
        v.z = fmaxf(fmaf(v.z, A, C), 0.0f);
        v.w = fmaxf(fmaf(v.w, A, C), 0.0f);
        p4[tid + i * 256] = v;
    }
}

// ---------------------------------------------------------------------------
extern "C" void kernel_launch(void* const* d_in, const int* in_sizes, int n_in,
                              void* d_out, int out_size, void* d_ws, size_t ws_size,
                              hipStream_t stream)
{
    const float* normals = (const float*)d_in[0];
    const float* walpha  = (const float*)d_in[1];
    const float* wbeta   = (const float*)d_in[2];
    const float* gamma   = (const float*)d_in[3];
    const float* beta    = (const float*)d_in[4];
    const int*   nidx    = (const int*)d_in[5];
    float* out = (float*)d_out;
    float* ws  = (float*)d_ws;

    if (ws_size >= WS_NEED) {
        // G-factorized path: 4x fewer exps. 3 dispatches, no atomics/memset.
        hipLaunchKernelGGL(fkc_g_kernel, dim3(2048), dim3(256), 0, stream,
                           normals, walpha, wbeta, ws + WS_G);
        hipLaunchKernelGGL(fkc_gather_kernel, dim3(1024), dim3(256), 0, stream,
                           ws + WS_G, nidx, out, ws);
        hipLaunchKernelGGL(fkc_bn2_kernel, dim3(B_DIM * M_DIM), dim3(256), 0, stream,
                           out, gamma, beta, ws);
    } else {
        // Proven 50.85us fallback (2 dispatches).
        hipLaunchKernelGGL(fb_feat_kernel, dim3(2048), dim3(256), 0, stream,
                           normals, walpha, wbeta, nidx, out, ws);
        hipLaunchKernelGGL(fb_bn_kernel, dim3(B_DIM * M_DIM), dim3(256), 0, stream,
                           out, gamma, beta, ws);
    }
}

// Round 12
// 53.812 us; speedup vs baseline: 1.3255x; 1.3255x over previous
//
#include <hip/hip_runtime.h>

// Problem constants (from reference setup_inputs)
#define B_DIM 8
#define F_DIM 16384
#define K_DIM 3
#define M_DIM 64
#define LOG2E 1.4426950408889634f

// ws float layout (deterministic, fully overwritten every launch):
//   [0, 32768)     : partial raw sums  slot = m*512 + b*64 + fc
//   [32768, 65536) : partial raw sumsq (same indexing)
// Raw = un-normalized sum of 16 exps (/16 folded into BN coefficients).
#define WS_Q 32768

// readlane: broadcast lane I's value of tv (wave-uniform result -> SGPR)
#define WGET(TV, I) __int_as_float(__builtin_amdgcn_readlane(__float_as_int(TV), (I)))

// ---------------------------------------------------------------------------
// Kernel 1: raw feat sums -> d_out, per-(m,b,fc) partials -> ws.
// grid = 2048 (b8 x mc4 x fc64), block = 256, 1 f/thread, 16 m/block.
// DS-pipe diet vs R7 (DS is a per-CU shared resource; it was ~17.6us of
// serialized occupancy):
//  - kernel-point table is pulled into SGPRs via one lane-indexed ds_read_b32
//    + 64 v_readlane per 4-m chunk (was 64 wave-uniform ds_read_b128);
//  - in-loop wave butterfly (6 DS ops/m) replaced by 1 ds_write_b32/m into a
//    stride-257 LDS row; one conflict-free epilogue fold per block.
// ---------------------------------------------------------------------------
__global__ __launch_bounds__(256) void fkc_feat_kernel(
    const float* __restrict__ normals,   // [B,3,F]
    const float* __restrict__ walpha,    // [M*4]
    const float* __restrict__ wbeta,     // [M*4]
    const int*   __restrict__ nidx,      // [B,F,K] int32
    float* __restrict__ feat_out,        // [B,M,F] raw sums
    float* __restrict__ ws)
{
    __shared__ float sWf[256];           // flat table: (mlocal*4+j)*4 + comp
    __shared__ float T[16 * 257];        // [m][f-local], stride 257 (bank-clean)
    __shared__ float sBS[16][4], sBQ[16][4];

    const int tid = threadIdx.x;
    const int b  = blockIdx.x >> 8;          // 256 blocks per batch
    const int mc = (blockIdx.x >> 6) & 3;    // m-chunk (16 m)
    const int fc = blockIdx.x & 63;          // f-chunk (256 f)

    // Build prescaled table (||p||^2==1 folded): one (m,j) entry per thread<64.
    if (tid < 64) {
        int idx = mc * 64 + tid;
        float a = walpha[idx], bb = wbeta[idx];
        float sa = sinf(a), ca = cosf(a);
        float sb = sinf(bb), cb = cosf(bb);
        float wx = sa * cb, wy = sa * sb, wz = ca;
        float w2 = wx * wx + wy * wy + wz * wz;
        sWf[tid * 4 + 0] = wx * 25.0f * LOG2E;
        sWf[tid * 4 + 1] = wy * 25.0f * LOG2E;
        sWf[tid * 4 + 2] = wz * 25.0f * LOG2E;
        sWf[tid * 4 + 3] = -12.5f * LOG2E * (w2 + 1.0f);
    }
    __syncthreads();

    const int f = (fc << 8) + tid;           // coalesced f
    const float* nb = normals + (size_t)b * 3 * F_DIM;
    float px[4], py[4], pz[4];
    px[0] = nb[f]; py[0] = nb[F_DIM + f]; pz[0] = nb[2 * F_DIM + f];
    const int* ib = nidx + ((size_t)b * F_DIM + f) * K_DIM;
#pragma unroll
    for (int k = 0; k < K_DIM; ++k) {
        int id = ib[k];
        px[k + 1] = nb[id]; py[k + 1] = nb[F_DIM + id]; pz[k + 1] = nb[2 * F_DIM + id];
    }

    const int lane = tid & 63;
    float* outb = feat_out + ((size_t)b * M_DIM + mc * 16) * F_DIM + f;

#pragma unroll 1                              // keep SGPR live-set to one chunk
    for (int c = 0; c < 4; ++c) {             // 4 chunks x 4 m
        float tv = sWf[c * 64 + lane];        // one DS read: 64 table floats/wave
#pragma unroll
        for (int ms = 0; ms < 4; ++ms) {
            float s0 = 0.f, s1 = 0.f, s2 = 0.f, s3 = 0.f;
#pragma unroll
            for (int j = 0; j < 4; ++j) {
                const int base = ms * 16 + j * 4;
                float wx = WGET(tv, base + 0);   // SGPR operands
                float wy = WGET(tv, base + 1);
                float wz = WGET(tv, base + 2);
                float ww = WGET(tv, base + 3);
                asm("" : "+v"(ww));              // force VGPR (1-SGPR/fma rule)
                s0 += __builtin_amdgcn_exp2f(fmaf(wx, px[0], fmaf(wy, py[0], fmaf(wz, pz[0], ww))));
                s1 += __builtin_amdgcn_exp2f(fmaf(wx, px[1], fmaf(wy, py[1], fmaf(wz, pz[1], ww))));
                s2 += __builtin_amdgcn_exp2f(fmaf(wx, px[2], fmaf(wy, py[2], fmaf(wz, pz[2], ww))));
                s3 += __builtin_amdgcn_exp2f(fmaf(wx, px[3], fmaf(wy, py[3], fmaf(wz, pz[3], ww))));
            }
            float S = (s0 + s1) + (s2 + s3);     // raw sum (no /16)
            const int m = c * 4 + ms;
            outb[(size_t)m * F_DIM] = S;
            T[m * 257 + tid] = S;                // 1 DS write (consecutive addrs)
        }
    }
    __syncthreads();

    // Epilogue: thread t -> (m = t&15, jj = t>>4); 16 b32 reads, banks
    // (m + 16*jj + i) mod 32 are distinct across a wave -> conflict-free.
    {
        const int m = tid & 15, jj = tid >> 4;
        const float* row = &T[m * 257 + jj * 16];
        float s = 0.f, q = 0.f;
#pragma unroll
        for (int i = 0; i < 16; ++i) { float v = row[i]; s += v; q = fmaf(v, v, q); }
        // fold the wave's 4 jj-slices (bits 4,5 of tid)
        s += __shfl_xor(s, 16, 64); q += __shfl_xor(q, 16, 64);
        s += __shfl_xor(s, 32, 64); q += __shfl_xor(q, 32, 64);
        const int wave = tid >> 6;
        if ((tid & 48) == 0) { sBS[m][wave] = s; sBQ[m][wave] = q; }
    }
    __syncthreads();
    if (tid < 16) {
        float s = (sBS[tid][0] + sBS[tid][1]) + (sBS[tid][2] + sBS[tid][3]);
        float q = (sBQ[tid][0] + sBQ[tid][1]) + (sBQ[tid][2] + sBQ[tid][3]);
        int slot = (mc * 16 + tid) * 512 + b * 64 + fc;
        ws[slot] = s;
        ws[WS_Q + slot] = q;
    }
}

// ---------------------------------------------------------------------------
// Kernel 2: stats + BN + ReLU (proven R10 version). grid = 512, block = 256.
// out holds RAW sums S (= 16*feat); /16 folded into coefficients:
//   out = relu((A/16)*S + (beta - meanF*A)),  A = gamma*rsqrt(var+eps)
// ---------------------------------------------------------------------------
__global__ __launch_bounds__(256) void fkc_bn_kernel(
    float* __restrict__ out,             // [B,M,F]
    const float* __restrict__ gamma,
    const float* __restrict__ beta,
    const float* __restrict__ ws)
{
    __shared__ float sS[4], sQ[4];
    __shared__ float sAC[2];
    const int row = blockIdx.x;              // b*64 + m
    const int m = row & 63;
    const int tid = threadIdx.x;
    const int wave = tid >> 6, lane = tid & 63;

    {   // fold this channel's 512 partials (2 per thread, L2-hot)
        float s = ws[m * 512 + tid]        + ws[m * 512 + tid + 256];
        float q = ws[WS_Q + m * 512 + tid] + ws[WS_Q + m * 512 + tid + 256];
#pragma unroll
        for (int off = 32; off >= 1; off >>= 1) {
            s += __shfl_xor(s, off, 64);
            q += __shfl_xor(q, off, 64);
        }
        if (lane == 0) { sS[wave] = s; sQ[wave] = q; }
    }
    __syncthreads();
    if (tid == 0) {
        float s = (sS[0] + sS[1]) + (sS[2] + sS[3]);
        float q = (sQ[0] + sQ[1]) + (sQ[2] + sQ[3]);
        const float invcnt = 1.0f / (float)(B_DIM * F_DIM);
        float meanS = s * invcnt;
        float meanF = meanS * (1.0f / 16.0f);
        float ef2   = q * invcnt * (1.0f / 256.0f);
        float var   = ef2 - meanF * meanF;
        float inv   = rsqrtf(var + 1e-5f);
        float A = gamma[m] * inv;
        sAC[0] = A * (1.0f / 16.0f);          // applied to raw S
        sAC[1] = beta[m] - meanF * A;
    }
    __syncthreads();

    const float A = sAC[0], C = sAC[1];
    float4* p4 = (float4*)(out + (size_t)row * F_DIM);
#pragma unroll
    for (int i = 0; i < 16; ++i) {           // 4096 float4 / 256 threads
        float4 v = p4[tid + i * 256];
        v.x = fmaxf(fmaf(v.x, A, C), 0.0f);
        v.y = fmaxf(fmaf(v.y, A, C), 0.0f);
        v.z = fmaxf(fmaf(v.z, A, C), 0.0f);
        v.w = fmaxf(fmaf(v.w, A, C), 0.0f);
        p4[tid + i * 256] = v;
    }
}

// ---------------------------------------------------------------------------
extern "C" void kernel_launch(void* const* d_in, const int* in_sizes, int n_in,
                              void* d_out, int out_size, void* d_ws, size_t ws_size,
                              hipStream_t stream)
{
    const float* normals = (const float*)d_in[0];
    const float* walpha  = (const float*)d_in[1];
    const float* wbeta   = (const float*)d_in[2];
    const float* gamma   = (const float*)d_in[3];
    const float* beta    = (const float*)d_in[4];
    const int*   nidx    = (const int*)d_in[5];
    float* out = (float*)d_out;
    float* ws  = (float*)d_ws;

    // 2 dispatches. No memset, no atomics: every ws slot used is
    // overwritten every launch (poison-safe).
    hipLaunchKernelGGL(fkc_feat_kernel, dim3(2048), dim3(256), 0, stream,
                       normals, walpha, wbeta, nidx, out, ws);
    hipLaunchKernelGGL(fkc_bn_kernel, dim3(B_DIM * M_DIM), dim3(256), 0, stream,
                       out, gamma, beta, ws);
}

// Round 13
// 49.736 us; speedup vs baseline: 1.4342x; 1.0820x over previous
//
#include <hip/hip_runtime.h>
#include <hip/hip_fp16.h>

// Problem constants (from reference setup_inputs)
#define B_DIM 8
#define F_DIM 16384
#define K_DIM 3
#define M_DIM 64
#define LOG2E 1.4426950408889634f

// ---- G-path ws layout (floats; every slot overwritten every launch) ----
//   [0, 65536)       : S partials  slot = m*1024 + b*128 + fc
//   [65536, 131072)  : Q partials  (same indexing)
//   float idx 131072 : G[b][f][64] as fp16 (16.8 MB)
#define WS_Q   65536
#define WS_G   131072                      // float index of G base
#define WS_NEED ((size_t)WS_G * 4 + (size_t)B_DIM * F_DIM * M_DIM * 2)

// ---- fallback ws layout (proven R7 path) ----
#define FB_WS_Q 32768

// ===========================================================================
// Kernel G: G[b,f,m] = sum_j exp2(arg(n_f, w_{m,j}))  packed to fp16.
// grid = 2048 (b8 x fc256 of 64 f), block = 256 = 64 f-lanes x 4 m-quarters.
// Per thread: 16 m x 4 j = 64 exps (4x fewer than recompute path's 256).
// ===========================================================================
__global__ __launch_bounds__(256) void fkc_g16_kernel(
    const float* __restrict__ normals,   // [B,3,F]
    const float* __restrict__ walpha,    // [M*4]
    const float* __restrict__ wbeta,     // [M*4]
    __half* __restrict__ G)              // [B,F,64] fp16
{
    __shared__ float4 sW[256];
    const int tid = threadIdx.x;
    {   // prescaled kernel-point table (||p||^2==1 folded in)
        float a = walpha[tid], b = wbeta[tid];
        float sa = sinf(a), ca = cosf(a);
        float sb = sinf(b), cb = cosf(b);
        float wx = sa * cb, wy = sa * sb, wz = ca;
        float w2 = wx * wx + wy * wy + wz * wz;
        sW[tid] = make_float4(wx * 25.0f * LOG2E, wy * 25.0f * LOG2E,
                              wz * 25.0f * LOG2E, -12.5f * LOG2E * (w2 + 1.0f));
    }
    __syncthreads();

    const int b  = blockIdx.x >> 8;          // 256 blocks per batch
    const int fc = blockIdx.x & 255;         // 64-f chunk
    const int fl = tid & 63, mq = tid >> 6;  // lane=f, wave=m-quarter
    const int f  = (fc << 6) + fl;

    const float* nb = normals + (size_t)b * 3 * F_DIM;
    const float px = nb[f], py = nb[F_DIM + f], pz = nb[2 * F_DIM + f];

    union { __half2 h2[8]; float4 f4[2]; } u;
#pragma unroll
    for (int r = 0; r < 8; ++r) {            // 2 m per r
        float g[2];
#pragma unroll
        for (int c = 0; c < 2; ++c) {
            const int m = mq * 16 + r * 2 + c;
            float4 w0 = sW[m * 4 + 0], w1 = sW[m * 4 + 1];
            float4 w2 = sW[m * 4 + 2], w3 = sW[m * 4 + 3];
            float e0 = __builtin_amdgcn_exp2f(fmaf(w0.x, px, fmaf(w0.y, py, fmaf(w0.z, pz, w0.w))));
            float e1 = __builtin_amdgcn_exp2f(fmaf(w1.x, px, fmaf(w1.y, py, fmaf(w1.z, pz, w1.w))));
            float e2 = __builtin_amdgcn_exp2f(fmaf(w2.x, px, fmaf(w2.y, py, fmaf(w2.z, pz, w2.w))));
            float e3 = __builtin_amdgcn_exp2f(fmaf(w3.x, px, fmaf(w3.y, py, fmaf(w3.z, pz, w3.w))));
            g[c] = (e0 + e1) + (e2 + e3);
        }
        u.h2[r] = __floats2half2_rn(g[0], g[1]);
    }
    float4* dst = (float4*)(G + ((size_t)(b * F_DIM + f)) * M_DIM + mq * 16);
    dst[0] = u.f4[0];
    dst[1] = u.f4[1];
}

// ===========================================================================
// Kernel GATHER: feat_raw[b,m,f] = G[f]+G[i1]+G[i2]+G[i3] (fp16 pk-adds),
// -> out (f32 raw sums) + per-(m,b,fc) partials via padded-LDS transpose.
// grid = 1024 (b8 x fc128 of 128 f), block = 256 = 128 f x 2 m-halves.
// Per thread: 4 rows x 64 B contiguous loads (4 dwordx4 each) — half the
// bytes AND half the load-instrs of the R11 f32 gather.
// ===========================================================================
__global__ __launch_bounds__(256) void fkc_gath16_kernel(
    const __half* __restrict__ G,        // [B,F,64] fp16
    const int*   __restrict__ nidx,      // [B,F,K]
    float* __restrict__ out,             // [B,M,F] raw sums
    float* __restrict__ ws)
{
    __shared__ float T[2][128][34];      // padded: 2-way conflicts max
    const int tid = threadIdx.x;
    const int b  = blockIdx.x >> 7;          // 128 blocks per batch
    const int fc = blockIdx.x & 127;         // 128-f chunk
    const int fl = tid & 127, mh = tid >> 7; // lane-major f, 2 m-halves
    const int f  = (fc << 7) + fl;

    const int* ib = nidx + ((size_t)(b * F_DIM + f)) * K_DIM;
    const int i1 = ib[0], i2 = ib[1], i3 = ib[2];

    const size_t gb = (size_t)b * F_DIM * M_DIM + (size_t)mh * 32;
    const float4* r0 = (const float4*)(G + gb + (size_t)f  * M_DIM);
    const float4* r1 = (const float4*)(G + gb + (size_t)i1 * M_DIM);
    const float4* r2 = (const float4*)(G + gb + (size_t)i2 * M_DIM);
    const float4* r3 = (const float4*)(G + gb + (size_t)i3 * M_DIM);

    union F4H { float4 f4; __half2 h2[4]; };
    float v[32];
#pragma unroll
    for (int c = 0; c < 4; ++c) {            // 4 x 16B chunks = 64 B
        F4H a, x, y, z, acc;
        a.f4 = r0[c]; x.f4 = r1[c]; y.f4 = r2[c]; z.f4 = r3[c];
#pragma unroll
        for (int k = 0; k < 4; ++k) {
            acc.h2[k] = __hadd2(__hadd2(a.h2[k], x.h2[k]), __hadd2(y.h2[k], z.h2[k]));
            float2 t = __half22float2(acc.h2[k]);
            v[c * 8 + k * 2]     = t.x;
            v[c * 8 + k * 2 + 1] = t.y;
        }
    }

    // raw feat -> out (coalesced per m across lanes)
    {
        float* ob = out + ((size_t)b * M_DIM + mh * 32) * F_DIM + f;
#pragma unroll
        for (int k = 0; k < 32; ++k) ob[(size_t)k * F_DIM] = v[k];
    }

    // ---- partials: pass A (sum), pass B (sumsq) via LDS transpose ----
    const int rmh = tid >> 7, rml = (tid >> 2) & 31, rfs = tid & 3;
    float ps;
#pragma unroll
    for (int k = 0; k < 32; ++k) T[mh][fl][k] = v[k];
    __syncthreads();
    {
        float s = 0.f;
#pragma unroll
        for (int i = 0; i < 32; ++i) s += T[rmh][rfs * 32 + i][rml];
        s += __shfl_xor(s, 1, 64);
        s += __shfl_xor(s, 2, 64);
        ps = s;                              // valid where rfs==0
    }
    __syncthreads();
#pragma unroll
    for (int k = 0; k < 32; ++k) T[mh][fl][k] = v[k] * v[k];
    __syncthreads();
    {
        float q = 0.f;
#pragma unroll
        for (int i = 0; i < 32; ++i) q += T[rmh][rfs * 32 + i][rml];
        q += __shfl_xor(q, 1, 64);
        q += __shfl_xor(q, 2, 64);
        if (rfs == 0) {
            int m = rmh * 32 + rml;
            int slot = m * 1024 + b * 128 + fc;
            ws[slot] = ps;
            ws[WS_Q + slot] = q;
        }
    }
}

// ===========================================================================
// Kernel BN: stats + BN + ReLU (R11-verified). grid = 512, block = 256.
// out holds RAW sums S (= 16*feat); /16 folded into coefficients.
// ===========================================================================
__global__ __launch_bounds__(256) void fkc_bn2_kernel(
    float* __restrict__ out,
    const float* __restrict__ gamma,
    const float* __restrict__ beta,
    const float* __restrict__ ws)
{
    __shared__ float sS[4], sQ[4];
    __shared__ float sAC[2];
    const int row = blockIdx.x;              // b*64 + m
    const int m = row & 63;
    const int tid = threadIdx.x;
    const int wave = tid >> 6, lane = tid & 63;

    {   // fold this channel's 1024 partials (4 per thread, L2-hot)
        const float* p = ws + m * 1024;
        const float* r = ws + WS_Q + m * 1024;
        float s = (p[tid] + p[tid + 256]) + (p[tid + 512] + p[tid + 768]);
        float q = (r[tid] + r[tid + 256]) + (r[tid + 512] + r[tid + 768]);
#pragma unroll
        for (int off = 32; off >= 1; off >>= 1) {
            s += __shfl_xor(s, off, 64);
            q += __shfl_xor(q, off, 64);
        }
        if (lane == 0) { sS[wave] = s; sQ[wave] = q; }
    }
    __syncthreads();
    if (tid == 0) {
        float s = (sS[0] + sS[1]) + (sS[2] + sS[3]);
        float q = (sQ[0] + sQ[1]) + (sQ[2] + sQ[3]);
        const float invcnt = 1.0f / (float)(B_DIM * F_DIM);
        float meanS = s * invcnt;
        float meanF = meanS * (1.0f / 16.0f);
        float ef2   = q * invcnt * (1.0f / 256.0f);
        float var   = ef2 - meanF * meanF;
        float inv   = rsqrtf(var + 1e-5f);
        float A = gamma[m] * inv;
        sAC[0] = A * (1.0f / 16.0f);          // applied to raw S
        sAC[1] = beta[m] - meanF * A;
    }
    __syncthreads();

    const float A = sAC[0], C = sAC[1];
    float4* p4 = (float4*)(out + (size_t)row * F_DIM);
#pragma unroll
    for (int i = 0; i < 16; ++i) {
        float4 v = p4[tid + i * 256];
        v.x = fmaxf(fmaf(v.x, A, C), 0.0f);
        v.y = fmaxf(fmaf(v.y, A, C), 0.0f);
        v.z = fmaxf(fmaf(v.z, A, C), 0.0f);
        v.w = fmaxf(fmaf(v.w, A, C), 0.0f);
        p4[tid + i * 256] = v;
    }
}

// ===========================================================================
// Fallback path: proven R7-style 2-dispatch pipeline (used iff ws too small).
// ===========================================================================
__global__ __launch_bounds__(256) void fb_feat_kernel(
    const float* __restrict__ normals, const float* __restrict__ walpha,
    const float* __restrict__ wbeta, const int* __restrict__ nidx,
    float* __restrict__ feat_out, float* __restrict__ ws)
{
    __shared__ float4 sW[64];
    __shared__ float sRS[16][32], sRQ[16][32];
    const int tid = threadIdx.x;
    const int b  = blockIdx.x >> 8;
    const int mc = (blockIdx.x >> 6) & 3;
    const int fc = blockIdx.x & 63;
    if (tid < 64) {
        int idx = mc * 64 + tid;
        float a = walpha[idx], bb = wbeta[idx];
        float sa = sinf(a), ca = cosf(a);
        float sb = sinf(bb), cb = cosf(bb);
        float wx = sa * cb, wy = sa * sb, wz = ca;
        float w2 = wx * wx + wy * wy + wz * wz;
        sW[tid] = make_float4(wx * 25.0f * LOG2E, wy * 25.0f * LOG2E,
                              wz * 25.0f * LOG2E, -12.5f * LOG2E * (w2 + 1.0f));
    }
    __syncthreads();
    const int f = (fc << 8) + tid;
    const float* nb = normals + (size_t)b * 3 * F_DIM;
    float px[4], py[4], pz[4];
    px[0] = nb[f]; py[0] = nb[F_DIM + f]; pz[0] = nb[2 * F_DIM + f];
    const int* ib = nidx + ((size_t)b * F_DIM + f) * K_DIM;
#pragma unroll
    for (int k = 0; k < K_DIM; ++k) {
        int id = ib[k];
        px[k + 1] = nb[id]; py[k + 1] = nb[F_DIM + id]; pz[k + 1] = nb[2 * F_DIM + id];
    }
    const int wave = tid >> 6, lane = tid & 63;
    float* outb = feat_out + ((size_t)b * M_DIM + mc * 16) * F_DIM + f;
#pragma unroll 2
    for (int m = 0; m < 16; ++m) {
        float s0 = 0.f, s1 = 0.f, s2 = 0.f, s3 = 0.f;
#pragma unroll
        for (int j = 0; j < 4; ++j) {
            float4 w = sW[m * 4 + j];
            s0 += __builtin_amdgcn_exp2f(fmaf(w.x, px[0], fmaf(w.y, py[0], fmaf(w.z, pz[0], w.w))));
            s1 += __builtin_amdgcn_exp2f(fmaf(w.x, px[1], fmaf(w.y, py[1], fmaf(w.z, pz[1], w.w))));
            s2 += __builtin_amdgcn_exp2f(fmaf(w.x, px[2], fmaf(w.y, py[2], fmaf(w.z, pz[2], w.w))));
            s3 += __builtin_amdgcn_exp2f(fmaf(w.x, px[3], fmaf(w.y, py[3], fmaf(w.z, pz[3], w.w))));
        }
        float fv = ((s0 + s1) + (s2 + s3)) * (1.0f / 16.0f);
        outb[(size_t)m * F_DIM] = fv;
        float s = fv, q = fv * fv;
        s += __shfl_xor(s, 8, 64);  q += __shfl_xor(q, 8, 64);
        s += __shfl_xor(s, 16, 64); q += __shfl_xor(q, 16, 64);
        s += __shfl_xor(s, 32, 64); q += __shfl_xor(q, 32, 64);
        if (lane < 8) { sRS[m][wave * 8 + lane] = s; sRQ[m][wave * 8 + lane] = q; }
    }
    __syncthreads();
    {
        const int m = tid >> 4, j = tid & 15;
        float s = sRS[m][j] + sRS[m][j + 16];
        float q = sRQ[m][j] + sRQ[m][j + 16];
        s += __shfl_xor(s, 1, 64);  q += __shfl_xor(q, 1, 64);
        s += __shfl_xor(s, 2, 64);  q += __shfl_xor(q, 2, 64);
        s += __shfl_xor(s, 4, 64);  q += __shfl_xor(q, 4, 64);
        s += __shfl_xor(s, 8, 64);  q += __shfl_xor(q, 8, 64);
        if (j == 0) {
            int slot = (mc * 16 + m) * 512 + b * 64 + fc;
            ws[slot] = s;
            ws[FB_WS_Q + slot] = q;
        }
    }
}

__global__ __launch_bounds__(256) void fb_bn_kernel(
    float* __restrict__ out, const float* __restrict__ gamma,
    const float* __restrict__ beta, const float* __restrict__ ws)
{
    __shared__ float sS[4], sQ[4];
    __shared__ float sAC[2];
    const int row = blockIdx.x;
    const int m = row & 63;
    const int tid = threadIdx.x;
    const int wave = tid >> 6, lane = tid & 63;
    {
        float s = ws[m * 512 + tid]           + ws[m * 512 + tid + 256];
        float q = ws[FB_WS_Q + m * 512 + tid] + ws[FB_WS_Q + m * 512 + tid + 256];
#pragma unroll
        for (int off = 32; off >= 1; off >>= 1) {
            s += __shfl_xor(s, off, 64);
            q += __shfl_xor(q, off, 64);
        }
        if (lane == 0) { sS[wave] = s; sQ[wave] = q; }
    }
    __syncthreads();
    if (tid == 0) {
        float s = (sS[0] + sS[1]) + (sS[2] + sS[3]);
        float q = (sQ[0] + sQ[1]) + (sQ[2] + sQ[3]);
        const float invcnt = 1.0f / (float)(B_DIM * F_DIM);
        float mean = s * invcnt;
        float var  = q * invcnt - mean * mean;
        float inv  = rsqrtf(var + 1e-5f);
        float A = gamma[m] * inv;
        sAC[0] = A;
        sAC[1] = beta[m] - mean * A;
    }
    __syncthreads();
    const float A = sAC[0], C = sAC[1];
    float4* p4 = (float4*)(out + (size_t)row * F_DIM);
#pragma unroll
    for (int i = 0; i < 16; ++i) {
        float4 v = p4[tid + i * 256];
        v.x = fmaxf(fmaf(v.x, A, C), 0.0f);
        v.y = fmaxf(fmaf(v.y, A, C), 0.0f);
        v.z = fmaxf(fmaf(v.z, A, C), 0.0f);
        v.w = fmaxf(fmaf(v.w, A, C), 0.0f);
        p4[tid + i * 256] = v;
    }
}

// ---------------------------------------------------------------------------
extern "C" void kernel_launch(void* const* d_in, const int* in_sizes, int n_in,
                              void* d_out, int out_size, void* d_ws, size_t ws_size,
                              hipStream_t stream)
{
    const float* normals = (const float*)d_in[0];
    const float* walpha  = (const float*)d_in[1];
    const float* wbeta   = (const float*)d_in[2];
    const float* gamma   = (const float*)d_in[3];
    const float* beta    = (const float*)d_in[4];
    const int*   nidx    = (const int*)d_in[5];
    float* out = (float*)d_out;
    float* ws  = (float*)d_ws;

    if (ws_size >= WS_NEED) {
        // fp16-G factorized path: 4x fewer exps, half the R11 gather traffic.
        __half* G = (__half*)(ws + WS_G);
        hipLaunchKernelGGL(fkc_g16_kernel, dim3(2048), dim3(256), 0, stream,
                           normals, walpha, wbeta, G);
        hipLaunchKernelGGL(fkc_gath16_kernel, dim3(1024), dim3(256), 0, stream,
                           G, nidx, out, ws);
        hipLaunchKernelGGL(fkc_bn2_kernel, dim3(B_DIM * M_DIM), dim3(256), 0, stream,
                           out, gamma, beta, ws);
    } else {
        // Proven fallback (2 dispatches).
        hipLaunchKernelGGL(fb_feat_kernel, dim3(2048), dim3(256), 0, stream,
                           normals, walpha, wbeta, nidx, out, ws);
        hipLaunchKernelGGL(fb_bn_kernel, dim3(B_DIM * M_DIM), dim3(256), 0, stream,
                           out, gamma, beta, ws);
    }
}

// Round 14
// 47.140 us; speedup vs baseline: 1.5131x; 1.0551x over previous
//
#include <hip/hip_runtime.h>
#include <hip/hip_fp16.h>

// Problem constants (from reference setup_inputs)
#define B_DIM 8
#define F_DIM 16384
#define K_DIM 3
#define M_DIM 64
#define LOG2E 1.4426950408889634f

// ---- G-path ws layout (floats; every slot overwritten every launch) ----
//   [0, 65536)       : S partials  slot = m*1024 + b*128 + fc
//   [65536, 131072)  : Q partials  (same indexing)
//   float idx 131072 : G[b][f][64] as fp16 (16.8 MB)
#define WS_Q   65536
#define WS_G   131072                      // float index of G base
#define WS_NEED ((size_t)WS_G * 4 + (size_t)B_DIM * F_DIM * M_DIM * 2)

// ---- fallback ws layout (proven R7 path) ----
#define FB_WS_Q 32768

// ===========================================================================
// Kernel G: G[b,f,m] = sum_j exp2(arg(n_f, w_{m,j}))  packed to fp16.
// grid = 2048 (b8 x fc256 of 64 f), block = 256 = 64 f-lanes x 4 m-quarters.
// Per thread: 16 m x 4 j = 64 exps (4x fewer than recompute path's 256).
// ===========================================================================
__global__ __launch_bounds__(256) void fkc_g16_kernel(
    const float* __restrict__ normals,   // [B,3,F]
    const float* __restrict__ walpha,    // [M*4]
    const float* __restrict__ wbeta,     // [M*4]
    __half* __restrict__ G)              // [B,F,64] fp16
{
    __shared__ float4 sW[256];
    const int tid = threadIdx.x;
    {   // prescaled kernel-point table (||p||^2==1 folded in)
        float a = walpha[tid], b = wbeta[tid];
        float sa = sinf(a), ca = cosf(a);
        float sb = sinf(b), cb = cosf(b);
        float wx = sa * cb, wy = sa * sb, wz = ca;
        float w2 = wx * wx + wy * wy + wz * wz;
        sW[tid] = make_float4(wx * 25.0f * LOG2E, wy * 25.0f * LOG2E,
                              wz * 25.0f * LOG2E, -12.5f * LOG2E * (w2 + 1.0f));
    }
    __syncthreads();

    const int b  = blockIdx.x >> 8;          // 256 blocks per batch
    const int fc = blockIdx.x & 255;         // 64-f chunk
    const int fl = tid & 63, mq = tid >> 6;  // lane=f, wave=m-quarter
    const int f  = (fc << 6) + fl;

    const float* nb = normals + (size_t)b * 3 * F_DIM;
    const float px = nb[f], py = nb[F_DIM + f], pz = nb[2 * F_DIM + f];

    union { __half2 h2[8]; float4 f4[2]; } u;
#pragma unroll
    for (int r = 0; r < 8; ++r) {            // 2 m per r
        float g[2];
#pragma unroll
        for (int c = 0; c < 2; ++c) {
            const int m = mq * 16 + r * 2 + c;
            float4 w0 = sW[m * 4 + 0], w1 = sW[m * 4 + 1];
            float4 w2 = sW[m * 4 + 2], w3 = sW[m * 4 + 3];
            float e0 = __builtin_amdgcn_exp2f(fmaf(w0.x, px, fmaf(w0.y, py, fmaf(w0.z, pz, w0.w))));
            float e1 = __builtin_amdgcn_exp2f(fmaf(w1.x, px, fmaf(w1.y, py, fmaf(w1.z, pz, w1.w))));
            float e2 = __builtin_amdgcn_exp2f(fmaf(w2.x, px, fmaf(w2.y, py, fmaf(w2.z, pz, w2.w))));
            float e3 = __builtin_amdgcn_exp2f(fmaf(w3.x, px, fmaf(w3.y, py, fmaf(w3.z, pz, w3.w))));
            g[c] = (e0 + e1) + (e2 + e3);
        }
        u.h2[r] = __floats2half2_rn(g[0], g[1]);
    }
    float4* dst = (float4*)(G + ((size_t)(b * F_DIM + f)) * M_DIM + mq * 16);
    dst[0] = u.f4[0];
    dst[1] = u.f4[1];
}

// ===========================================================================
// Kernel GATHER: feat_raw[b,m,f] = G[f]+G[i1]+G[i2]+G[i3] (fp16 pk-adds),
// -> out (f32 raw sums) + per-(m,b,fc) partials via padded-LDS transpose.
// grid = 1024, block = 256 = 128 f x 2 m-halves.
// XCD-PINNED: b = blockIdx&7 -> with round-robin dispatch, XCD j handles only
// batch j, whose G slab (2.1 MB fp16) fits its 4 MB L2 -> neighbor-row reads
// (each row reused ~4x) become L2 hits instead of L3.
// Single-pass transpose: square during the read (halved DS ops vs R13).
// ===========================================================================
__global__ __launch_bounds__(256) void fkc_gath16_kernel(
    const __half* __restrict__ G,        // [B,F,64] fp16
    const int*   __restrict__ nidx,      // [B,F,K]
    float* __restrict__ out,             // [B,M,F] raw sums
    float* __restrict__ ws)
{
    __shared__ float T[2][128][34];      // padded
    const int tid = threadIdx.x;
    const int b  = blockIdx.x & 7;           // XCD-pinned batch
    const int fc = blockIdx.x >> 3;          // 128-f chunk (0..127)
    const int fl = tid & 127, mh = tid >> 7; // lane-major f, 2 m-halves
    const int f  = (fc << 7) + fl;

    const int* ib = nidx + ((size_t)(b * F_DIM + f)) * K_DIM;
    const int i1 = ib[0], i2 = ib[1], i3 = ib[2];

    const size_t gb = (size_t)b * F_DIM * M_DIM + (size_t)mh * 32;
    const float4* r0 = (const float4*)(G + gb + (size_t)f  * M_DIM);
    const float4* r1 = (const float4*)(G + gb + (size_t)i1 * M_DIM);
    const float4* r2 = (const float4*)(G + gb + (size_t)i2 * M_DIM);
    const float4* r3 = (const float4*)(G + gb + (size_t)i3 * M_DIM);

    union F4H { float4 f4; __half2 h2[4]; };
    float v[32];
#pragma unroll
    for (int c = 0; c < 4; ++c) {            // 4 x 16B chunks = 64 B
        F4H a, x, y, z, acc;
        a.f4 = r0[c]; x.f4 = r1[c]; y.f4 = r2[c]; z.f4 = r3[c];
#pragma unroll
        for (int k = 0; k < 4; ++k) {
            acc.h2[k] = __hadd2(__hadd2(a.h2[k], x.h2[k]), __hadd2(y.h2[k], z.h2[k]));
            float2 t = __half22float2(acc.h2[k]);
            v[c * 8 + k * 2]     = t.x;
            v[c * 8 + k * 2 + 1] = t.y;
        }
    }

    // raw feat -> out (coalesced per m across lanes)
    {
        float* ob = out + ((size_t)b * M_DIM + mh * 32) * F_DIM + f;
#pragma unroll
        for (int k = 0; k < 32; ++k) ob[(size_t)k * F_DIM] = v[k];
    }

    // ---- partials: ONE transpose pass; square during the read ----
#pragma unroll
    for (int k = 0; k < 32; ++k) T[mh][fl][k] = v[k];
    __syncthreads();
    {
        const int rmh = tid >> 7, rml = (tid >> 2) & 31, rfs = tid & 3;
        float s = 0.f, q = 0.f;
#pragma unroll
        for (int i = 0; i < 32; ++i) {
            float val = T[rmh][rfs * 32 + i][rml];
            s += val;
            q = fmaf(val, val, q);
        }
        s += __shfl_xor(s, 1, 64);  q += __shfl_xor(q, 1, 64);
        s += __shfl_xor(s, 2, 64);  q += __shfl_xor(q, 2, 64);
        if (rfs == 0) {
            int m = rmh * 32 + rml;
            int slot = m * 1024 + b * 128 + fc;
            ws[slot] = s;
            ws[WS_Q + slot] = q;
        }
    }
}

// ===========================================================================
// Kernel BN: stats + BN + ReLU (R11-verified). grid = 512, block = 256.
// out holds RAW sums S (= 16*feat); /16 folded into coefficients.
// ===========================================================================
__global__ __launch_bounds__(256) void fkc_bn2_kernel(
    float* __restrict__ out,
    const float* __restrict__ gamma,
    const float* __restrict__ beta,
    const float* __restrict__ ws)
{
    __shared__ float sS[4], sQ[4];
    __shared__ float sAC[2];
    const int row = blockIdx.x;              // b*64 + m
    const int m = row & 63;
    const int tid = threadIdx.x;
    const int wave = tid >> 6, lane = tid & 63;

    {   // fold this channel's 1024 partials (4 per thread, L2-hot)
        const float* p = ws + m * 1024;
        const float* r = ws + WS_Q + m * 1024;
        float s = (p[tid] + p[tid + 256]) + (p[tid + 512] + p[tid + 768]);
        float q = (r[tid] + r[tid + 256]) + (r[tid + 512] + r[tid + 768]);
#pragma unroll
        for (int off = 32; off >= 1; off >>= 1) {
            s += __shfl_xor(s, off, 64);
            q += __shfl_xor(q, off, 64);
        }
        if (lane == 0) { sS[wave] = s; sQ[wave] = q; }
    }
    __syncthreads();
    if (tid == 0) {
        float s = (sS[0] + sS[1]) + (sS[2] + sS[3]);
        float q = (sQ[0] + sQ[1]) + (sQ[2] + sQ[3]);
        const float invcnt = 1.0f / (float)(B_DIM * F_DIM);
        float meanS = s * invcnt;
        float meanF = meanS * (1.0f / 16.0f);
        float ef2   = q * invcnt * (1.0f / 256.0f);
        float var   = ef2 - meanF * meanF;
        float inv   = rsqrtf(var + 1e-5f);
        float A = gamma[m] * inv;
        sAC[0] = A * (1.0f / 16.0f);          // applied to raw S
        sAC[1] = beta[m] - meanF * A;
    }
    __syncthreads();

    const float A = sAC[0], C = sAC[1];
    float4* p4 = (float4*)(out + (size_t)row * F_DIM);
#pragma unroll
    for (int i = 0; i < 16; ++i) {
        float4 v = p4[tid + i * 256];
        v.x = fmaxf(fmaf(v.x, A, C), 0.0f);
        v.y = fmaxf(fmaf(v.y, A, C), 0.0f);
        v.z = fmaxf(fmaf(v.z, A, C), 0.0f);
        v.w = fmaxf(fmaf(v.w, A, C), 0.0f);
        p4[tid + i * 256] = v;
    }
}

// ===========================================================================
// Fallback path: proven R7-style 2-dispatch pipeline (used iff ws too small).
// ===========================================================================
__global__ __launch_bounds__(256) void fb_feat_kernel(
    const float* __restrict__ normals, const float* __restrict__ walpha,
    const float* __restrict__ wbeta, const int* __restrict__ nidx,
    float* __restrict__ feat_out, float* __restrict__ ws)
{
    __shared__ float4 sW[64];
    __shared__ float sRS[16][32], sRQ[16][32];
    const int tid = threadIdx.x;
    const int b  = blockIdx.x >> 8;
    const int mc = (blockIdx.x >> 6) & 3;
    const int fc = blockIdx.x & 63;
    if (tid < 64) {
        int idx = mc * 64 + tid;
        float a = walpha[idx], bb = wbeta[idx];
        float sa = sinf(a), ca = cosf(a);
        float sb = sinf(bb), cb = cosf(bb);
        float wx = sa * cb, wy = sa * sb, wz = ca;
        float w2 = wx * wx + wy * wy + wz * wz;
        sW[tid] = make_float4(wx * 25.0f * LOG2E, wy * 25.0f * LOG2E,
                              wz * 25.0f * LOG2E, -12.5f * LOG2E * (w2 + 1.0f));
    }
    __syncthreads();
    const int f = (fc << 8) + tid;
    const float* nb = normals + (size_t)b * 3 * F_DIM;
    float px[4], py[4], pz[4];
    px[0] = nb[f]; py[0] = nb[F_DIM + f]; pz[0] = nb[2 * F_DIM + f];
    const int* ib = nidx + ((size_t)b * F_DIM + f) * K_DIM;
#pragma unroll
    for (int k = 0; k < K_DIM; ++k) {
        int id = ib[k];
        px[k + 1] = nb[id]; py[k + 1] = nb[F_DIM + id]; pz[k + 1] = nb[2 * F_DIM + id];
    }
    const int wave = tid >> 6, lane = tid & 63;
    float* outb = feat_out + ((size_t)b * M_DIM + mc * 16) * F_DIM + f;
#pragma unroll 2
    for (int m = 0; m < 16; ++m) {
        float s0 = 0.f, s1 = 0.f, s2 = 0.f, s3 = 0.f;
#pragma unroll
        for (int j = 0; j < 4; ++j) {
            float4 w = sW[m * 4 + j];
            s0 += __builtin_amdgcn_exp2f(fmaf(w.x, px[0], fmaf(w.y, py[0], fmaf(w.z, pz[0], w.w))));
            s1 += __builtin_amdgcn_exp2f(fmaf(w.x, px[1], fmaf(w.y, py[1], fmaf(w.z, pz[1], w.w))));
            s2 += __builtin_amdgcn_exp2f(fmaf(w.x, px[2], fmaf(w.y, py[2], fmaf(w.z, pz[2], w.w))));
            s3 += __builtin_amdgcn_exp2f(fmaf(w.x, px[3], fmaf(w.y, py[3], fmaf(w.z, pz[3], w.w))));
        }
        float fv = ((s0 + s1) + (s2 + s3)) * (1.0f / 16.0f);
        outb[(size_t)m * F_DIM] = fv;
        float s = fv, q = fv * fv;
        s += __shfl_xor(s, 8, 64);  q += __shfl_xor(q, 8, 64);
        s += __shfl_xor(s, 16, 64); q += __shfl_xor(q, 16, 64);
        s += __shfl_xor(s, 32, 64); q += __shfl_xor(q, 32, 64);
        if (lane < 8) { sRS[m][wave * 8 + lane] = s; sRQ[m][wave * 8 + lane] = q; }
    }
    __syncthreads();
    {
        const int m = tid >> 4, j = tid & 15;
        float s = sRS[m][j] + sRS[m][j + 16];
        float q = sRQ[m][j] + sRQ[m][j + 16];
        s += __shfl_xor(s, 1, 64);  q += __shfl_xor(q, 1, 64);
        s += __shfl_xor(s, 2, 64);  q += __shfl_xor(q, 2, 64);
        s += __shfl_xor(s, 4, 64);  q += __shfl_xor(q, 4, 64);
        s += __shfl_xor(s, 8, 64);  q += __shfl_xor(q, 8, 64);
        if (j == 0) {
            int slot = (mc * 16 + m) * 512 + b * 64 + fc;
            ws[slot] = s;
            ws[FB_WS_Q + slot] = q;
        }
    }
}

__global__ __launch_bounds__(256) void fb_bn_kernel(
    float* __restrict__ out, const float* __restrict__ gamma,
    const float* __restrict__ beta, const float* __restrict__ ws)
{
    __shared__ float sS[4], sQ[4];
    __shared__ float sAC[2];
    const int row = blockIdx.x;
    const int m = row & 63;
    const int tid = threadIdx.x;
    const int wave = tid >> 6, lane = tid & 63;
    {
        float s = ws[m * 512 + tid]           + ws[m * 512 + tid + 256];
        float q = ws[FB_WS_Q + m * 512 + tid] + ws[FB_WS_Q + m * 512 + tid + 256];
#pragma unroll
        for (int off = 32; off >= 1; off >>= 1) {
            s += __shfl_xor(s, off, 64);
            q += __shfl_xor(q, off, 64);
        }
        if (lane == 0) { sS[wave] = s; sQ[wave] = q; }
    }
    __syncthreads();
    if (tid == 0) {
        float s = (sS[0] + sS[1]) + (sS[2] + sS[3]);
        float q = (sQ[0] + sQ[1]) + (sQ[2] + sQ[3]);
        const float invcnt = 1.0f / (float)(B_DIM * F_DIM);
        float mean = s * invcnt;
        float var  = q * invcnt - mean * mean;
        float inv  = rsqrtf(var + 1e-5f);
        float A = gamma[m] * inv;
        sAC[0] = A;
        sAC[1] = beta[m] - mean * A;
    }
    __syncthreads();
    const float A = sAC[0], C = sAC[1];
    float4* p4 = (float4*)(out + (size_t)row * F_DIM);
#pragma unroll
    for (int i = 0; i < 16; ++i) {
        float4 v = p4[tid + i * 256];
        v.x = fmaxf(fmaf(v.x, A, C), 0.0f);
        v.y = fmaxf(fmaf(v.y, A, C), 0.0f);
        v.z = fmaxf(fmaf(v.z, A, C), 0.0f);
        v.w = fmaxf(fmaf(v.w, A, C), 0.0f);
        p4[tid + i * 256] = v;
    }
}

// ---------------------------------------------------------------------------
extern "C" void kernel_launch(void* const* d_in, const int* in_sizes, int n_in,
                              void* d_out, int out_size, void* d_ws, size_t ws_size,
                              hipStream_t stream)
{
    const float* normals = (const float*)d_in[0];
    const float* walpha  = (const float*)d_in[1];
    const float* wbeta   = (const float*)d_in[2];
    const float* gamma   = (const float*)d_in[3];
    const float* beta    = (const float*)d_in[4];
    const int*   nidx    = (const int*)d_in[5];
    float* out = (float*)d_out;
    float* ws  = (float*)d_ws;

    if (ws_size >= WS_NEED) {
        // fp16-G factorized path: 4x fewer exps, L2-pinned gather.
        __half* G = (__half*)(ws + WS_G);
        hipLaunchKernelGGL(fkc_g16_kernel, dim3(2048), dim3(256), 0, stream,
                           normals, walpha, wbeta, G);
        hipLaunchKernelGGL(fkc_gath16_kernel, dim3(1024), dim3(256), 0, stream,
                           G, nidx, out, ws);
        hipLaunchKernelGGL(fkc_bn2_kernel, dim3(B_DIM * M_DIM), dim3(256), 0, stream,
                           out, gamma, beta, ws);
    } else {
        // Proven fallback (2 dispatches).
        hipLaunchKernelGGL(fb_feat_kernel, dim3(2048), dim3(256), 0, stream,
                           normals, walpha, wbeta, nidx, out, ws);
        hipLaunchKernelGGL(fb_bn_kernel, dim3(B_DIM * M_DIM), dim3(256), 0, stream,
                           out, gamma, beta, ws);
    }
}